// Round 9
// baseline (231.141 us; speedup 1.0000x reference)
//
#include <hip/hip_runtime.h>
#include <hip/hip_bf16.h>

// WitnessEncoder: B=8, N=2048, VOCAB=32000, EMBED=256, HIDDEN=512
// f32 inputs -> bf16 MFMA with f32 accumulate.
// colsum[b,m] = sum_n softplus(sim[n,m]); sim symmetric -> upper-triangle tiles only.
// witness[b,d] = (1/N) sum_m colsum[b,m] * hidden[b,m,d]; sim never materialized.
// R9: sim_colsum restructured to NO-LDS direct-to-register MFMA. R8 showed the
//     2-barrier K-loop is ~60% vmcnt(0)-drain-bound at K=512 (MfmaUtil 14%, VALU 17%,
//     HBM 12%, nothing saturated). Fragments for 16x16x32 bf16 with B^T layout are
//     16B-contiguous -> one global_load_dwordx4 per frag, offset-immediate across the
//     fully-unrolled K-loop; no barriers, loads overlap MFMA via compiler vmcnt(N).
//     L2-resident per-XCD batch slab (grid (8,136) batch->XCD, verified R8).
//     GEMMs keep the working LDS structure with (256,4).

typedef __bf16 bf16;
typedef __bf16 bf16x4 __attribute__((ext_vector_type(4)));
typedef __bf16 bf16x8 __attribute__((ext_vector_type(8)));
typedef float f32x4 __attribute__((ext_vector_type(4)));

#define MFMA_BF16(a, b, c) __builtin_amdgcn_mfma_f32_16x16x32_bf16((a), (b), (c), 0, 0, 0)

__device__ __forceinline__ void async_copy16(const void* gptr, void* ldsptr) {
  __builtin_amdgcn_global_load_lds(
      (const __attribute__((address_space(1))) void*)gptr,
      (__attribute__((address_space(3))) void*)ldsptr, 16, 0, 0);
}

// softplus(x) = x/2 + ln(2cosh(x/2)) ~= x/2 + ln2 + x^2/8 - x^4/192 + x^6/2880  (|x|<=1.2: err<1e-4)
__device__ __forceinline__ float softplus_poly(float x) {
  const float u = x * x;
  float p = fmaf(u, 3.472222e-4f, -5.208333e-3f);
  p = fmaf(p, u, 0.125f);
  return fmaf(x, 0.5f, 0.69314718f) + p * u;
}

// ---- LDS K-step machinery for the MLP GEMMs (unchanged, R8-verified) ----
#define STAGE16(K0)                                                               \
  { _Pragma("unroll")                                                             \
    for (int i_ = 0; i_ < 4; ++i_) {                                              \
      const int c_ = t + 256 * i_;                                                \
      const int row_ = c_ >> 3;                                                   \
      const int kk_ = ((c_ & 7) ^ (row_ & 7)) * 8;                                \
      async_copy16(pA + (size_t)row_ * LDK + (kk_ + (K0)), &As[c_ * 8]);          \
      async_copy16(pB + (size_t)row_ * LDK + (kk_ + (K0)), &Bs[c_ * 8]);          \
    } }

#define COMPUTE64()                                                               \
  { _Pragma("unroll")                                                             \
    for (int ks_ = 0; ks_ < 2; ++ks_) {                                           \
      const int swz_ = ((ks_ * 4 + lq) ^ (lr & 7)) * 8;                           \
      bf16x8 af_[4], bf_[4];                                                      \
      _Pragma("unroll")                                                           \
      for (int i_ = 0; i_ < 4; ++i_)                                              \
        af_[i_] = *(const bf16x8*)&As[(wm * 64 + i_ * 16 + lr) * 64 + swz_];      \
      _Pragma("unroll")                                                           \
      for (int j_ = 0; j_ < 4; ++j_)                                              \
        bf_[j_] = *(const bf16x8*)&Bs[(wn * 64 + j_ * 16 + lr) * 64 + swz_];      \
      _Pragma("unroll")                                                           \
      for (int i_ = 0; i_ < 4; ++i_)                                              \
        _Pragma("unroll")                                                         \
        for (int j_ = 0; j_ < 4; ++j_)                                            \
          acc[i_][j_] = MFMA_BF16(af_[i_], bf_[j_], acc[i_][j_]);                 \
    } }

#define KSTEP(K0) STAGE16(K0) __syncthreads(); COMPUTE64() __syncthreads();

// Fused: embedding gather+convert, W1/W2 convert, zero-init of sq/colsum/witness.
__global__ __launch_bounds__(256)
void fused_prep(const int* __restrict__ tokens, const float* __restrict__ emb,
                const float* __restrict__ W1, const float* __restrict__ W2,
                bf16* __restrict__ embeds_b, bf16* __restrict__ W1b, bf16* __restrict__ W2b,
                float* __restrict__ zeros /* sq|colsum|witness, 36864 floats */)
{
  int tid = blockIdx.x * 256 + threadIdx.x;
  if (tid < 1048576) {                       // gather: 16384 rows x 64 chunks
    const int row = tid >> 6;
    const int c4 = (tid & 63) * 4;
    const int tok = tokens[row];
    const f32x4 v = *(const f32x4*)&emb[(size_t)tok * 256 + c4];
    bf16x4 o;
    o[0] = (bf16)v[0]; o[1] = (bf16)v[1]; o[2] = (bf16)v[2]; o[3] = (bf16)v[3];
    *(bf16x4*)&embeds_b[(size_t)row * 256 + c4] = o;
    return;
  }
  tid -= 1048576;
  if (tid < 32768) {                         // W1: 512x256
    const f32x4 v = *(const f32x4*)&W1[(size_t)tid * 4];
    bf16x4 o;
    o[0] = (bf16)v[0]; o[1] = (bf16)v[1]; o[2] = (bf16)v[2]; o[3] = (bf16)v[3];
    *(bf16x4*)&W1b[(size_t)tid * 4] = o;
    return;
  }
  tid -= 32768;
  if (tid < 65536) {                         // W2: 512x512
    const f32x4 v = *(const f32x4*)&W2[(size_t)tid * 4];
    bf16x4 o;
    o[0] = (bf16)v[0]; o[1] = (bf16)v[1]; o[2] = (bf16)v[2]; o[3] = (bf16)v[3];
    *(bf16x4*)&W2b[(size_t)tid * 4] = o;
    return;
  }
  tid -= 65536;
  if (tid < 9216)                            // zero 36864 floats
    *(f32x4*)&zeros[(size_t)tid * 4] = (f32x4){0.f, 0.f, 0.f, 0.f};
}

// C[m,n] = epi( sum_k A[m,k]*Bw[n,k] + bias[n] ). 128x128 tile, K-steps unrolled.
// SQ: atomically accumulate row sums-of-squares of C into sq[global row].
template <bool RELU, bool SQ, int K>
__global__ __launch_bounds__(256, 4)
void gemm_bt(const bf16* __restrict__ A, const bf16* __restrict__ Bw,
             const float* __restrict__ bias, bf16* __restrict__ C,
             float* __restrict__ sq, int N)
{
  __shared__ __align__(16) bf16 As[128 * 64];
  __shared__ __align__(16) bf16 Bs[128 * 64];
  const int m0 = blockIdx.x * 128;
  const int n0 = blockIdx.y * 128;
  const int t = threadIdx.x;
  const int lane = t & 63;
  const int w = t >> 6;
  const int wm = w >> 1, wn = w & 1;
  const int lr = lane & 15;
  const int lq = lane >> 4;
  const bf16* pA = A + (size_t)m0 * K;
  const bf16* pB = Bw + (size_t)n0 * K;
  const int LDK = K;

  f32x4 acc[4][4];
#pragma unroll
  for (int i = 0; i < 4; ++i)
#pragma unroll
    for (int j = 0; j < 4; ++j)
      acc[i][j] = (f32x4){0.f, 0.f, 0.f, 0.f};

  KSTEP(0) KSTEP(64) KSTEP(128) KSTEP(192)
  if constexpr (K > 256) { KSTEP(256) KSTEP(320) KSTEP(384) KSTEP(448) }

  // C/D layout: col = lane&15, row = (lane>>4)*4 + r
  float bv4[4];
#pragma unroll
  for (int j = 0; j < 4; ++j) {
    const int col = n0 + wn * 64 + j * 16 + lr;
    const float bv = bias[col];
    bv4[j] = bv;
#pragma unroll
    for (int i = 0; i < 4; ++i) {
      const int rbase = m0 + wm * 64 + i * 16 + lq * 4;
#pragma unroll
      for (int r = 0; r < 4; ++r) {
        float v = acc[i][j][r] + bv;
        if (RELU) v = fmaxf(v, 0.0f);
        C[(size_t)(rbase + r) * N + col] = (bf16)v;
      }
    }
  }
  if (SQ) {
#pragma unroll
    for (int i = 0; i < 4; ++i)
#pragma unroll
      for (int r = 0; r < 4; ++r) {
        float s2 = 0.f;
#pragma unroll
        for (int j = 0; j < 4; ++j) {
          const float v = acc[i][j][r] + bv4[j];
          s2 += v * v;
        }
        s2 += __shfl_xor(s2, 1, 64);
        s2 += __shfl_xor(s2, 2, 64);
        s2 += __shfl_xor(s2, 4, 64);
        s2 += __shfl_xor(s2, 8, 64);
        if (lr == 0)
          atomicAdd(&sq[m0 + wm * 64 + i * 16 + lq * 4 + r], s2);
      }
  }
}

// Upper-triangle tile (I,J): T[i,j]=softplus(dot(h_n,h_m)*rsqrt(sq_n)*rsqrt(sq_m)).
// NO-LDS: A/B fragments loaded straight from global (16B each, offset-immediate over
// the fully-unrolled K loop); no barriers in the K loop at all.
// grid (8,136): blockIdx.x = batch -> XCD (linear%8) for private-L2 locality.
__global__ __launch_bounds__(256)
void sim_colsum(const bf16* __restrict__ hidden, const float* __restrict__ sq,
                float* __restrict__ colsum)
{
  __shared__ float colacc[256];   // [2][128]
  __shared__ float rowacc[256];   // [2][128]

  const int b = blockIdx.x;
  const int p = blockIdx.y;
  // closed-form triangular decode: p -> (I,J), I<=J, 16 tiles/side
  int I = (int)((33.0f - sqrtf((float)(1089 - 8 * p))) * 0.5f);
  while (p < I * 16 - ((I - 1) * I) / 2) --I;
  while (p >= (I + 1) * 16 - (I * (I + 1)) / 2) ++I;
  const int J = I + p - (I * 16 - ((I - 1) * I) / 2);
  const bool diag = (I == J);
  const bf16* base = hidden + (size_t)b * (2048 * 512);
  const float* sqb = sq + (size_t)b * 2048;
  float* csb = colsum + (size_t)b * 2048;
  const int n0 = I * 128;   // A rows (sim rows)
  const int m0 = J * 128;   // B rows (sim cols)
  const int t = threadIdx.x, lane = t & 63, w = t >> 6;
  const int wm = w >> 1, wn = w & 1, lr = lane & 15, lq = lane >> 4;

  // per-lane row base pointers (loop-invariant; k offsets are immediates)
  const bf16* pa[4];
  const bf16* pb[4];
#pragma unroll
  for (int i = 0; i < 4; ++i)
    pa[i] = base + (size_t)(n0 + wm * 64 + i * 16 + lr) * 512 + lq * 8;
#pragma unroll
  for (int j = 0; j < 4; ++j)
    pb[j] = base + (size_t)(m0 + wn * 64 + j * 16 + lr) * 512 + lq * 8;

  f32x4 acc[4][4];
#pragma unroll
  for (int i = 0; i < 4; ++i)
#pragma unroll
    for (int j = 0; j < 4; ++j)
      acc[i][j] = (f32x4){0.f, 0.f, 0.f, 0.f};

#pragma unroll
  for (int k0 = 0; k0 < 512; k0 += 32) {
    bf16x8 af[4], bfr[4];
#pragma unroll
    for (int i = 0; i < 4; ++i) af[i] = *(const bf16x8*)(pa[i] + k0);
#pragma unroll
    for (int j = 0; j < 4; ++j) bfr[j] = *(const bf16x8*)(pb[j] + k0);
#pragma unroll
    for (int i = 0; i < 4; ++i)
#pragma unroll
      for (int j = 0; j < 4; ++j)
        acc[i][j] = MFMA_BF16(af[i], bfr[j], acc[i][j]);
  }

  // epilogue: inline inverse norms, softplus(poly), col- and row-sums
  f32x4 rv[4];
#pragma unroll
  for (int i = 0; i < 4; ++i) {
    const f32x4 s4 = *(const f32x4*)&sqb[n0 + wm * 64 + i * 16 + lq * 4];
#pragma unroll
    for (int u = 0; u < 4; ++u) rv[i][u] = rsqrtf(fmaxf(s4[u], 1e-24f));
  }
  float csum[4];
  float rsum[4][4];
#pragma unroll
  for (int j = 0; j < 4; ++j) csum[j] = 0.f;
#pragma unroll
  for (int i = 0; i < 4; ++i)
#pragma unroll
    for (int r = 0; r < 4; ++r) rsum[i][r] = 0.f;

#pragma unroll
  for (int j = 0; j < 4; ++j) {
    const float cv = rsqrtf(fmaxf(sqb[m0 + wn * 64 + j * 16 + lr], 1e-24f));
#pragma unroll
    for (int i = 0; i < 4; ++i)
#pragma unroll
      for (int r = 0; r < 4; ++r) {
        const float x = acc[i][j][r] * rv[i][r] * cv;   // |x| <= ~1
        const float s = softplus_poly(x);
        csum[j] += s;
        rsum[i][r] += s;
      }
  }
#pragma unroll
  for (int j = 0; j < 4; ++j) {
    float s = csum[j];
    s += __shfl_xor(s, 16, 64);
    s += __shfl_xor(s, 32, 64);
    if (lq == 0) colacc[wm * 128 + wn * 64 + j * 16 + lr] = s;
  }
  if (!diag) {
#pragma unroll
    for (int i = 0; i < 4; ++i)
#pragma unroll
      for (int r = 0; r < 4; ++r) {
        float s = rsum[i][r];
        s += __shfl_xor(s, 1, 64);
        s += __shfl_xor(s, 2, 64);
        s += __shfl_xor(s, 4, 64);
        s += __shfl_xor(s, 8, 64);
        if (lr == 0) rowacc[wn * 128 + wm * 64 + i * 16 + lq * 4 + r] = s;
      }
  }
  __syncthreads();
  if (t < 128) {
    atomicAdd(&csb[m0 + t], colacc[t] + colacc[128 + t]);
  } else if (!diag) {
    const int rr = t - 128;
    atomicAdd(&csb[n0 + rr], rowacc[rr] + rowacc[128 + rr]);
  }
}

// witness[b,d] += sum_{m in 64-chunk} colsum[b,m] * hidden[b,m,d]   (bf16x8 vectorized)
__global__ __launch_bounds__(256)
void witness_partial(const float* __restrict__ colsum, const bf16* __restrict__ hidden,
                     float* __restrict__ witness)
{
  const int mc = blockIdx.x;        // 0..31 (64-m chunks)
  const int b  = blockIdx.y;        // 0..7
  const int t = threadIdx.x;
  const int msub = t >> 6;          // 0..3 (wave-uniform)
  const int dg = t & 63;            // d-group: d = dg*8 .. dg*8+7
  const bf16* hb = hidden + (size_t)b * (2048 * 512);
  const float* cp = colsum + (size_t)b * 2048;
  float acc[8];
#pragma unroll
  for (int u = 0; u < 8; ++u) acc[u] = 0.f;
  const int mbeg = mc * 64 + msub * 16;
#pragma unroll 4
  for (int i = 0; i < 16; ++i) {
    const int m = mbeg + i;
    const float cw = cp[m];
    const bf16x8 v = *(const bf16x8*)&hb[(size_t)m * 512 + dg * 8];
#pragma unroll
    for (int u = 0; u < 8; ++u) acc[u] += cw * (float)v[u];
  }
  __shared__ float red[4][512];
#pragma unroll
  for (int u = 0; u < 8; ++u) red[msub][dg * 8 + u] = acc[u];
  __syncthreads();
  if (msub == 0) {
#pragma unroll
    for (int u = 0; u < 8; ++u) {
      const int d = dg * 8 + u;
      atomicAdd(&witness[(size_t)b * 512 + d],
                red[0][d] + red[1][d] + red[2][d] + red[3][d]);
    }
  }
}

// out[b,g] = bp[g] + (1/2048) * dot(witness[b,:], Wp[g,:])
__global__ __launch_bounds__(64)
void final_proj(const float* __restrict__ witness, const float* __restrict__ Wp,
                const float* __restrict__ bpv, float* __restrict__ out)
{
  const int b = blockIdx.x >> 3;
  const int gc = blockIdx.x & 7;
  const int g = gc * 64 + threadIdx.x;
  __shared__ float wit[512];
#pragma unroll
  for (int u = 0; u < 8; ++u)
    wit[threadIdx.x * 8 + u] = witness[(size_t)b * 512 + threadIdx.x * 8 + u];
  __syncthreads();
  const float* wrow = Wp + (size_t)g * 512;
  float acc = 0.f;
  for (int d0 = 0; d0 < 512; d0 += 4) {
    const f32x4 v = *(const f32x4*)&wrow[d0];
#pragma unroll
    for (int u = 0; u < 4; ++u) acc += v[u] * wit[d0 + u];
  }
  out[(size_t)b * 512 + g] = bpv[g] + acc * (1.0f / 2048.0f);
}

extern "C" void kernel_launch(void* const* d_in, const int* in_sizes, int n_in,
                              void* d_out, int out_size, void* d_ws, size_t ws_size,
                              hipStream_t stream) {
  (void)in_sizes; (void)n_in; (void)out_size; (void)ws_size;
  const int*   tokens = (const int*)d_in[0];
  const float* emb    = (const float*)d_in[1];
  const float* W1     = (const float*)d_in[2];
  const float* b1     = (const float*)d_in[3];
  const float* W2     = (const float*)d_in[4];
  const float* b2     = (const float*)d_in[5];
  const float* Wp     = (const float*)d_in[6];
  const float* bp     = (const float*)d_in[7];
  float* out = (float*)d_out;

  char* w = (char*)d_ws;
  bf16*  embeds_b = (bf16*)(w);                               // 8 MB
  bf16*  W1_b     = (bf16*)(w + (size_t) 8 * 1024 * 1024);    // 256 KB
  bf16*  W2_b     = (bf16*)(w + (size_t) 9 * 1024 * 1024);    // 512 KB
  bf16*  h_buf    = (bf16*)(w + (size_t)10 * 1024 * 1024);    // 16 MB
  bf16*  hidden   = (bf16*)(w + (size_t)26 * 1024 * 1024);    // 16 MB
  char*  zbase    =        (w + (size_t)42 * 1024 * 1024);
  float* sq       = (float*)(zbase);                          // 64 KB  (zeroed in prep)
  float* colsum   = (float*)(zbase + 64 * 1024);              // 64 KB  (zeroed in prep)
  float* witness  = (float*)(zbase + 128 * 1024);             // 16 KB  (zeroed in prep)

  // 1) gather+convert embeds, convert W1/W2, zero accumulators (one kernel)
  fused_prep<<<4516, 256, 0, stream>>>(tokens, emb, W1, W2, embeds_b, W1_b, W2_b, sq);
  // 2) h = relu(embeds @ W1^T + b1)
  gemm_bt<true,  false, 256><<<dim3(128, 4), 256, 0, stream>>>(embeds_b, W1_b, b1, h_buf, nullptr, 512);
  // 3) hidden = h @ W2^T + b2, fused ||row||^2 partials
  gemm_bt<false, true,  512><<<dim3(128, 4), 256, 0, stream>>>(h_buf, W2_b, b2, hidden, sq, 512);
  // 4) colsum via symmetric upper-triangle tiles (batch -> XCD), no-LDS direct MFMA
  sim_colsum<<<dim3(8, 136), 256, 0, stream>>>(hidden, sq, colsum);
  // 5) witness partials (vectorized)
  witness_partial<<<dim3(32, 8), 256, 0, stream>>>(colsum, hidden, witness);
  // 6) out = witness/2048 @ Wp^T + bp
  final_proj<<<64, 64, 0, stream>>>(witness, Wp, bp, out);
}

// Round 10
// 171.840 us; speedup vs baseline: 1.3451x; 1.3451x over previous
//
#include <hip/hip_runtime.h>
#include <hip/hip_bf16.h>

// WitnessEncoder: B=8, N=2048, VOCAB=32000, EMBED=256, HIDDEN=512
// f32 inputs -> bf16 MFMA with f32 accumulate.
// colsum[b,m] = sum_n softplus(sim[n,m]); sim symmetric -> upper-triangle tiles only.
// witness[b,d] = (1/N) sum_m colsum[b,m] * hidden[b,m,d]; sim never materialized.
// R10: R9's no-LDS sim REVERTED (uncoalesced 16-transaction frag loads -> latency-bound,
//      100us). sim back to R8's LDS K-loop but with 512-thread blocks / 8 waves of
//      32x64 sub-tiles: acc 32 AGPR (vs 64) -> 24-32 waves/CU (vs 16) to hide the
//      vmcnt(0) barrier drain. GEMMs keep R8 (256,4) structure exactly.

typedef __bf16 bf16;
typedef __bf16 bf16x4 __attribute__((ext_vector_type(4)));
typedef __bf16 bf16x8 __attribute__((ext_vector_type(8)));
typedef float f32x4 __attribute__((ext_vector_type(4)));

#define MFMA_BF16(a, b, c) __builtin_amdgcn_mfma_f32_16x16x32_bf16((a), (b), (c), 0, 0, 0)

__device__ __forceinline__ void async_copy16(const void* gptr, void* ldsptr) {
  __builtin_amdgcn_global_load_lds(
      (const __attribute__((address_space(1))) void*)gptr,
      (__attribute__((address_space(3))) void*)ldsptr, 16, 0, 0);
}

// softplus(x) = x/2 + ln(2cosh(x/2)) ~= x/2 + ln2 + x^2/8 - x^4/192 + x^6/2880  (|x|<=1.2: err<1e-4)
__device__ __forceinline__ float softplus_poly(float x) {
  const float u = x * x;
  float p = fmaf(u, 3.472222e-4f, -5.208333e-3f);
  p = fmaf(p, u, 0.125f);
  return fmaf(x, 0.5f, 0.69314718f) + p * u;
}

// ---- LDS K-step machinery for the MLP GEMMs (R8-verified, 256 threads) ----
#define STAGE16(K0)                                                               \
  { _Pragma("unroll")                                                             \
    for (int i_ = 0; i_ < 4; ++i_) {                                              \
      const int c_ = t + 256 * i_;                                                \
      const int row_ = c_ >> 3;                                                   \
      const int kk_ = ((c_ & 7) ^ (row_ & 7)) * 8;                                \
      async_copy16(pA + (size_t)row_ * LDK + (kk_ + (K0)), &As[c_ * 8]);          \
      async_copy16(pB + (size_t)row_ * LDK + (kk_ + (K0)), &Bs[c_ * 8]);          \
    } }

#define COMPUTE64()                                                               \
  { _Pragma("unroll")                                                             \
    for (int ks_ = 0; ks_ < 2; ++ks_) {                                           \
      const int swz_ = ((ks_ * 4 + lq) ^ (lr & 7)) * 8;                           \
      bf16x8 af_[4], bf_[4];                                                      \
      _Pragma("unroll")                                                           \
      for (int i_ = 0; i_ < 4; ++i_)                                              \
        af_[i_] = *(const bf16x8*)&As[(wm * 64 + i_ * 16 + lr) * 64 + swz_];      \
      _Pragma("unroll")                                                           \
      for (int j_ = 0; j_ < 4; ++j_)                                              \
        bf_[j_] = *(const bf16x8*)&Bs[(wn * 64 + j_ * 16 + lr) * 64 + swz_];      \
      _Pragma("unroll")                                                           \
      for (int i_ = 0; i_ < 4; ++i_)                                              \
        _Pragma("unroll")                                                         \
        for (int j_ = 0; j_ < 4; ++j_)                                            \
          acc[i_][j_] = MFMA_BF16(af_[i_], bf_[j_], acc[i_][j_]);                 \
    } }

#define KSTEP(K0) STAGE16(K0) __syncthreads(); COMPUTE64() __syncthreads();

// ---- 512-thread sim variant: 8 waves, each 32(m-rows of A-side)x64 ----
#define STAGE16_W8(K0)                                                            \
  { _Pragma("unroll")                                                             \
    for (int i_ = 0; i_ < 2; ++i_) {                                              \
      const int c_ = t + 512 * i_;                                                \
      const int row_ = c_ >> 3;                                                   \
      const int kk_ = ((c_ & 7) ^ (row_ & 7)) * 8;                                \
      async_copy16(pA + (size_t)row_ * 512 + (kk_ + (K0)), &As[c_ * 8]);          \
      async_copy16(pB + (size_t)row_ * 512 + (kk_ + (K0)), &Bs[c_ * 8]);          \
    } }

#define COMPUTE64_W8()                                                            \
  { _Pragma("unroll")                                                             \
    for (int ks_ = 0; ks_ < 2; ++ks_) {                                           \
      const int swz_ = ((ks_ * 4 + lq) ^ (lr & 7)) * 8;                           \
      bf16x8 af_[2], bf_[4];                                                      \
      _Pragma("unroll")                                                           \
      for (int i_ = 0; i_ < 2; ++i_)                                              \
        af_[i_] = *(const bf16x8*)&As[(wm * 32 + i_ * 16 + lr) * 64 + swz_];      \
      _Pragma("unroll")                                                           \
      for (int j_ = 0; j_ < 4; ++j_)                                              \
        bf_[j_] = *(const bf16x8*)&Bs[(wn * 64 + j_ * 16 + lr) * 64 + swz_];      \
      _Pragma("unroll")                                                           \
      for (int i_ = 0; i_ < 2; ++i_)                                              \
        _Pragma("unroll")                                                         \
        for (int j_ = 0; j_ < 4; ++j_)                                            \
          acc[i_][j_] = MFMA_BF16(af_[i_], bf_[j_], acc[i_][j_]);                 \
    } }

#define KSTEP_W8(K0) STAGE16_W8(K0) __syncthreads(); COMPUTE64_W8() __syncthreads();

// Fused: embedding gather+convert, W1/W2 convert, zero-init of sq/colsum/witness.
__global__ __launch_bounds__(256)
void fused_prep(const int* __restrict__ tokens, const float* __restrict__ emb,
                const float* __restrict__ W1, const float* __restrict__ W2,
                bf16* __restrict__ embeds_b, bf16* __restrict__ W1b, bf16* __restrict__ W2b,
                float* __restrict__ zeros /* sq|colsum|witness, 36864 floats */)
{
  int tid = blockIdx.x * 256 + threadIdx.x;
  if (tid < 1048576) {                       // gather: 16384 rows x 64 chunks
    const int row = tid >> 6;
    const int c4 = (tid & 63) * 4;
    const int tok = tokens[row];
    const f32x4 v = *(const f32x4*)&emb[(size_t)tok * 256 + c4];
    bf16x4 o;
    o[0] = (bf16)v[0]; o[1] = (bf16)v[1]; o[2] = (bf16)v[2]; o[3] = (bf16)v[3];
    *(bf16x4*)&embeds_b[(size_t)row * 256 + c4] = o;
    return;
  }
  tid -= 1048576;
  if (tid < 32768) {                         // W1: 512x256
    const f32x4 v = *(const f32x4*)&W1[(size_t)tid * 4];
    bf16x4 o;
    o[0] = (bf16)v[0]; o[1] = (bf16)v[1]; o[2] = (bf16)v[2]; o[3] = (bf16)v[3];
    *(bf16x4*)&W1b[(size_t)tid * 4] = o;
    return;
  }
  tid -= 32768;
  if (tid < 65536) {                         // W2: 512x512
    const f32x4 v = *(const f32x4*)&W2[(size_t)tid * 4];
    bf16x4 o;
    o[0] = (bf16)v[0]; o[1] = (bf16)v[1]; o[2] = (bf16)v[2]; o[3] = (bf16)v[3];
    *(bf16x4*)&W2b[(size_t)tid * 4] = o;
    return;
  }
  tid -= 65536;
  if (tid < 9216)                            // zero 36864 floats
    *(f32x4*)&zeros[(size_t)tid * 4] = (f32x4){0.f, 0.f, 0.f, 0.f};
}

// C[m,n] = epi( sum_k A[m,k]*Bw[n,k] + bias[n] ). 128x128 tile, K-steps unrolled.
// SQ: atomically accumulate row sums-of-squares of C into sq[global row].
template <bool RELU, bool SQ, int K>
__global__ __launch_bounds__(256, 4)
void gemm_bt(const bf16* __restrict__ A, const bf16* __restrict__ Bw,
             const float* __restrict__ bias, bf16* __restrict__ C,
             float* __restrict__ sq, int N)
{
  __shared__ __align__(16) bf16 As[128 * 64];
  __shared__ __align__(16) bf16 Bs[128 * 64];
  const int m0 = blockIdx.x * 128;
  const int n0 = blockIdx.y * 128;
  const int t = threadIdx.x;
  const int lane = t & 63;
  const int w = t >> 6;
  const int wm = w >> 1, wn = w & 1;
  const int lr = lane & 15;
  const int lq = lane >> 4;
  const bf16* pA = A + (size_t)m0 * K;
  const bf16* pB = Bw + (size_t)n0 * K;
  const int LDK = K;

  f32x4 acc[4][4];
#pragma unroll
  for (int i = 0; i < 4; ++i)
#pragma unroll
    for (int j = 0; j < 4; ++j)
      acc[i][j] = (f32x4){0.f, 0.f, 0.f, 0.f};

  KSTEP(0) KSTEP(64) KSTEP(128) KSTEP(192)
  if constexpr (K > 256) { KSTEP(256) KSTEP(320) KSTEP(384) KSTEP(448) }

  // C/D layout: col = lane&15, row = (lane>>4)*4 + r
  float bv4[4];
#pragma unroll
  for (int j = 0; j < 4; ++j) {
    const int col = n0 + wn * 64 + j * 16 + lr;
    const float bv = bias[col];
    bv4[j] = bv;
#pragma unroll
    for (int i = 0; i < 4; ++i) {
      const int rbase = m0 + wm * 64 + i * 16 + lq * 4;
#pragma unroll
      for (int r = 0; r < 4; ++r) {
        float v = acc[i][j][r] + bv;
        if (RELU) v = fmaxf(v, 0.0f);
        C[(size_t)(rbase + r) * N + col] = (bf16)v;
      }
    }
  }
  if (SQ) {
#pragma unroll
    for (int i = 0; i < 4; ++i)
#pragma unroll
      for (int r = 0; r < 4; ++r) {
        float s2 = 0.f;
#pragma unroll
        for (int j = 0; j < 4; ++j) {
          const float v = acc[i][j][r] + bv4[j];
          s2 += v * v;
        }
        s2 += __shfl_xor(s2, 1, 64);
        s2 += __shfl_xor(s2, 2, 64);
        s2 += __shfl_xor(s2, 4, 64);
        s2 += __shfl_xor(s2, 8, 64);
        if (lr == 0)
          atomicAdd(&sq[m0 + wm * 64 + i * 16 + lq * 4 + r], s2);
      }
  }
}

// Upper-triangle tile (I,J): T[i,j]=softplus(dot(h_n,h_m)*rsqrt(sq_n)*rsqrt(sq_m)).
// 512 threads / 8 waves, each 32x64 sub-tile (32 AGPR acc) -> more waves/CU to hide
// the barrier drain. col-sums -> atomic colsum[J]; if I<J row-sums -> colsum[I].
// grid (8,136): blockIdx.x = batch -> XCD (linear%8) for private-L2 locality.
__global__ __launch_bounds__(512)
void sim_colsum(const bf16* __restrict__ hidden, const float* __restrict__ sq,
                float* __restrict__ colsum)
{
  __shared__ __align__(16) bf16 As[128 * 64];
  __shared__ __align__(16) bf16 Bs[128 * 64];
  // epilogue arrays alias As (dead after final K-step barrier) -> LDS stays 32768 B
  float* colacc = (float*)As;          // [4][128]
  float* rowacc = (float*)As + 512;    // [2][128]

  const int b = blockIdx.x;
  const int p = blockIdx.y;
  // closed-form triangular decode: p -> (I,J), I<=J, 16 tiles/side
  int I = (int)((33.0f - sqrtf((float)(1089 - 8 * p))) * 0.5f);
  while (p < I * 16 - ((I - 1) * I) / 2) --I;
  while (p >= (I + 1) * 16 - (I * (I + 1)) / 2) ++I;
  const int J = I + p - (I * 16 - ((I - 1) * I) / 2);
  const bool diag = (I == J);
  const bf16* base = hidden + (size_t)b * (2048 * 512);
  const float* sqb = sq + (size_t)b * 2048;
  float* csb = colsum + (size_t)b * 2048;
  const int n0 = I * 128;   // A rows (sim rows)
  const int m0 = J * 128;   // B rows (sim cols)
  const int t = threadIdx.x, lane = t & 63, w = t >> 6;   // w in 0..7
  const int wm = w >> 1, wn = w & 1, lr = lane & 15, lq = lane >> 4;  // wm 0..3
  const bf16* pA = base + (size_t)n0 * 512;
  const bf16* pB = base + (size_t)m0 * 512;

  f32x4 acc[2][4];
#pragma unroll
  for (int i = 0; i < 2; ++i)
#pragma unroll
    for (int j = 0; j < 4; ++j)
      acc[i][j] = (f32x4){0.f, 0.f, 0.f, 0.f};

  KSTEP_W8(0) KSTEP_W8(64) KSTEP_W8(128) KSTEP_W8(192)
  KSTEP_W8(256) KSTEP_W8(320) KSTEP_W8(384) KSTEP_W8(448)

  // epilogue: inline inverse norms, softplus(poly), col- and row-sums
  f32x4 rv[2];
#pragma unroll
  for (int i = 0; i < 2; ++i) {
    const f32x4 s4 = *(const f32x4*)&sqb[n0 + wm * 32 + i * 16 + lq * 4];
#pragma unroll
    for (int u = 0; u < 4; ++u) rv[i][u] = rsqrtf(fmaxf(s4[u], 1e-24f));
  }
  float csum[4];
  float rsum[2][4];
#pragma unroll
  for (int j = 0; j < 4; ++j) csum[j] = 0.f;
#pragma unroll
  for (int i = 0; i < 2; ++i)
#pragma unroll
    for (int r = 0; r < 4; ++r) rsum[i][r] = 0.f;

#pragma unroll
  for (int j = 0; j < 4; ++j) {
    const float cv = rsqrtf(fmaxf(sqb[m0 + wn * 64 + j * 16 + lr], 1e-24f));
#pragma unroll
    for (int i = 0; i < 2; ++i)
#pragma unroll
      for (int r = 0; r < 4; ++r) {
        const float x = acc[i][j][r] * rv[i][r] * cv;   // |x| <= ~1
        const float s = softplus_poly(x);
        csum[j] += s;
        rsum[i][r] += s;
      }
  }
  // column sums: reduce over lane-quads (rows): lanes l, l^16, l^32, l^48
#pragma unroll
  for (int j = 0; j < 4; ++j) {
    float s = csum[j];
    s += __shfl_xor(s, 16, 64);
    s += __shfl_xor(s, 32, 64);
    if (lq == 0) colacc[wm * 128 + wn * 64 + j * 16 + lr] = s;
  }
  // row sums: reduce over lr lanes (cols) within quad
  if (!diag) {
#pragma unroll
    for (int i = 0; i < 2; ++i)
#pragma unroll
      for (int r = 0; r < 4; ++r) {
        float s = rsum[i][r];
        s += __shfl_xor(s, 1, 64);
        s += __shfl_xor(s, 2, 64);
        s += __shfl_xor(s, 4, 64);
        s += __shfl_xor(s, 8, 64);
        if (lr == 0) rowacc[wn * 128 + wm * 32 + i * 16 + lq * 4 + r] = s;
      }
  }
  __syncthreads();
  if (t < 128) {
    atomicAdd(&csb[m0 + t], colacc[t] + colacc[128 + t] + colacc[256 + t] + colacc[384 + t]);
  } else if (t < 256 && !diag) {
    const int rr = t - 128;
    atomicAdd(&csb[n0 + rr], rowacc[rr] + rowacc[128 + rr]);
  }
}

// witness[b,d] += sum_{m in 64-chunk} colsum[b,m] * hidden[b,m,d]   (bf16x8 vectorized)
__global__ __launch_bounds__(256)
void witness_partial(const float* __restrict__ colsum, const bf16* __restrict__ hidden,
                     float* __restrict__ witness)
{
  const int mc = blockIdx.x;        // 0..31 (64-m chunks)
  const int b  = blockIdx.y;        // 0..7
  const int t = threadIdx.x;
  const int msub = t >> 6;          // 0..3 (wave-uniform)
  const int dg = t & 63;            // d-group: d = dg*8 .. dg*8+7
  const bf16* hb = hidden + (size_t)b * (2048 * 512);
  const float* cp = colsum + (size_t)b * 2048;
  float acc[8];
#pragma unroll
  for (int u = 0; u < 8; ++u) acc[u] = 0.f;
  const int mbeg = mc * 64 + msub * 16;
#pragma unroll 4
  for (int i = 0; i < 16; ++i) {
    const int m = mbeg + i;
    const float cw = cp[m];
    const bf16x8 v = *(const bf16x8*)&hb[(size_t)m * 512 + dg * 8];
#pragma unroll
    for (int u = 0; u < 8; ++u) acc[u] += cw * (float)v[u];
  }
  __shared__ float red[4][512];
#pragma unroll
  for (int u = 0; u < 8; ++u) red[msub][dg * 8 + u] = acc[u];
  __syncthreads();
  if (msub == 0) {
#pragma unroll
    for (int u = 0; u < 8; ++u) {
      const int d = dg * 8 + u;
      atomicAdd(&witness[(size_t)b * 512 + d],
                red[0][d] + red[1][d] + red[2][d] + red[3][d]);
    }
  }
}

// out[b,g] = bp[g] + (1/2048) * dot(witness[b,:], Wp[g,:])
__global__ __launch_bounds__(64)
void final_proj(const float* __restrict__ witness, const float* __restrict__ Wp,
                const float* __restrict__ bpv, float* __restrict__ out)
{
  const int b = blockIdx.x >> 3;
  const int gc = blockIdx.x & 7;
  const int g = gc * 64 + threadIdx.x;
  __shared__ float wit[512];
#pragma unroll
  for (int u = 0; u < 8; ++u)
    wit[threadIdx.x * 8 + u] = witness[(size_t)b * 512 + threadIdx.x * 8 + u];
  __syncthreads();
  const float* wrow = Wp + (size_t)g * 512;
  float acc = 0.f;
  for (int d0 = 0; d0 < 512; d0 += 4) {
    const f32x4 v = *(const f32x4*)&wrow[d0];
#pragma unroll
    for (int u = 0; u < 4; ++u) acc += v[u] * wit[d0 + u];
  }
  out[(size_t)b * 512 + g] = bpv[g] + acc * (1.0f / 2048.0f);
}

extern "C" void kernel_launch(void* const* d_in, const int* in_sizes, int n_in,
                              void* d_out, int out_size, void* d_ws, size_t ws_size,
                              hipStream_t stream) {
  (void)in_sizes; (void)n_in; (void)out_size; (void)ws_size;
  const int*   tokens = (const int*)d_in[0];
  const float* emb    = (const float*)d_in[1];
  const float* W1     = (const float*)d_in[2];
  const float* b1     = (const float*)d_in[3];
  const float* W2     = (const float*)d_in[4];
  const float* b2     = (const float*)d_in[5];
  const float* Wp     = (const float*)d_in[6];
  const float* bp     = (const float*)d_in[7];
  float* out = (float*)d_out;

  char* w = (char*)d_ws;
  bf16*  embeds_b = (bf16*)(w);                               // 8 MB
  bf16*  W1_b     = (bf16*)(w + (size_t) 8 * 1024 * 1024);    // 256 KB
  bf16*  W2_b     = (bf16*)(w + (size_t) 9 * 1024 * 1024);    // 512 KB
  bf16*  h_buf    = (bf16*)(w + (size_t)10 * 1024 * 1024);    // 16 MB
  bf16*  hidden   = (bf16*)(w + (size_t)26 * 1024 * 1024);    // 16 MB
  char*  zbase    =        (w + (size_t)42 * 1024 * 1024);
  float* sq       = (float*)(zbase);                          // 64 KB  (zeroed in prep)
  float* colsum   = (float*)(zbase + 64 * 1024);              // 64 KB  (zeroed in prep)
  float* witness  = (float*)(zbase + 128 * 1024);             // 16 KB  (zeroed in prep)

  // 1) gather+convert embeds, convert W1/W2, zero accumulators (one kernel)
  fused_prep<<<4516, 256, 0, stream>>>(tokens, emb, W1, W2, embeds_b, W1_b, W2_b, sq);
  // 2) h = relu(embeds @ W1^T + b1)
  gemm_bt<true,  false, 256><<<dim3(128, 4), 256, 0, stream>>>(embeds_b, W1_b, b1, h_buf, nullptr, 512);
  // 3) hidden = h @ W2^T + b2, fused ||row||^2 partials
  gemm_bt<false, true,  512><<<dim3(128, 4), 256, 0, stream>>>(h_buf, W2_b, b2, hidden, sq, 512);
  // 4) colsum via symmetric upper-triangle tiles (batch -> XCD), 8-wave blocks
  sim_colsum<<<dim3(8, 136), 512, 0, stream>>>(hidden, sq, colsum);
  // 5) witness partials (vectorized)
  witness_partial<<<dim3(32, 8), 256, 0, stream>>>(colsum, hidden, witness);
  // 6) out = witness/2048 @ Wp^T + bp
  final_proj<<<64, 64, 0, stream>>>(witness, Wp, bp, out);
}

// Round 11
// 161.725 us; speedup vs baseline: 1.4292x; 1.0625x over previous
//
#include <hip/hip_runtime.h>
#include <hip/hip_bf16.h>

// WitnessEncoder: B=8, N=2048, VOCAB=32000, EMBED=256, HIDDEN=512
// f32 inputs -> bf16 MFMA with f32 accumulate.
// colsum[b,m] = sum_n softplus(sim[n,m]); sim symmetric -> upper-triangle tiles only.
// witness[b,d] = (1/N) sum_m colsum[b,m] * hidden[b,m,d]; sim never materialized.
// R11: 8-wave (512-thread) blocks for the MLP GEMMs too -- R10 proved the 8x(32x64)
//      sub-tile config (32 AGPR acc -> ~32 waves/CU) hides the vmcnt(0) barrier
//      drain better than 4x(64x64) (sim 47.3 -> <43us). Same 32KB LDS, same swizzle.

typedef __bf16 bf16;
typedef __bf16 bf16x4 __attribute__((ext_vector_type(4)));
typedef __bf16 bf16x8 __attribute__((ext_vector_type(8)));
typedef float f32x4 __attribute__((ext_vector_type(4)));

#define MFMA_BF16(a, b, c) __builtin_amdgcn_mfma_f32_16x16x32_bf16((a), (b), (c), 0, 0, 0)

__device__ __forceinline__ void async_copy16(const void* gptr, void* ldsptr) {
  __builtin_amdgcn_global_load_lds(
      (const __attribute__((address_space(1))) void*)gptr,
      (__attribute__((address_space(3))) void*)ldsptr, 16, 0, 0);
}

// softplus(x) = x/2 + ln(2cosh(x/2)) ~= x/2 + ln2 + x^2/8 - x^4/192 + x^6/2880  (|x|<=1.2: err<1e-4)
__device__ __forceinline__ float softplus_poly(float x) {
  const float u = x * x;
  float p = fmaf(u, 3.472222e-4f, -5.208333e-3f);
  p = fmaf(p, u, 0.125f);
  return fmaf(x, 0.5f, 0.69314718f) + p * u;
}

// ---- 512-thread / 8-wave K-step machinery (R10-verified in sim) ----
// requires locals: t, lr, lq, wm(0..3), wn(0..1), pA, pB, LDK, As, Bs, acc[2][4]
#define STAGE16_W8(K0)                                                            \
  { _Pragma("unroll")                                                             \
    for (int i_ = 0; i_ < 2; ++i_) {                                              \
      const int c_ = t + 512 * i_;                                                \
      const int row_ = c_ >> 3;                                                   \
      const int kk_ = ((c_ & 7) ^ (row_ & 7)) * 8;                                \
      async_copy16(pA + (size_t)row_ * LDK + (kk_ + (K0)), &As[c_ * 8]);          \
      async_copy16(pB + (size_t)row_ * LDK + (kk_ + (K0)), &Bs[c_ * 8]);          \
    } }

#define COMPUTE64_W8()                                                            \
  { _Pragma("unroll")                                                             \
    for (int ks_ = 0; ks_ < 2; ++ks_) {                                           \
      const int swz_ = ((ks_ * 4 + lq) ^ (lr & 7)) * 8;                           \
      bf16x8 af_[2], bf_[4];                                                      \
      _Pragma("unroll")                                                           \
      for (int i_ = 0; i_ < 2; ++i_)                                              \
        af_[i_] = *(const bf16x8*)&As[(wm * 32 + i_ * 16 + lr) * 64 + swz_];      \
      _Pragma("unroll")                                                           \
      for (int j_ = 0; j_ < 4; ++j_)                                              \
        bf_[j_] = *(const bf16x8*)&Bs[(wn * 64 + j_ * 16 + lr) * 64 + swz_];      \
      _Pragma("unroll")                                                           \
      for (int i_ = 0; i_ < 2; ++i_)                                              \
        _Pragma("unroll")                                                         \
        for (int j_ = 0; j_ < 4; ++j_)                                            \
          acc[i_][j_] = MFMA_BF16(af_[i_], bf_[j_], acc[i_][j_]);                 \
    } }

#define KSTEP_W8(K0) STAGE16_W8(K0) __syncthreads(); COMPUTE64_W8() __syncthreads();

// Fused: embedding gather+convert, W1/W2 convert, zero-init of sq/colsum/witness.
__global__ __launch_bounds__(256)
void fused_prep(const int* __restrict__ tokens, const float* __restrict__ emb,
                const float* __restrict__ W1, const float* __restrict__ W2,
                bf16* __restrict__ embeds_b, bf16* __restrict__ W1b, bf16* __restrict__ W2b,
                float* __restrict__ zeros /* sq|colsum|witness, 36864 floats */)
{
  int tid = blockIdx.x * 256 + threadIdx.x;
  if (tid < 1048576) {                       // gather: 16384 rows x 64 chunks
    const int row = tid >> 6;
    const int c4 = (tid & 63) * 4;
    const int tok = tokens[row];
    const f32x4 v = *(const f32x4*)&emb[(size_t)tok * 256 + c4];
    bf16x4 o;
    o[0] = (bf16)v[0]; o[1] = (bf16)v[1]; o[2] = (bf16)v[2]; o[3] = (bf16)v[3];
    *(bf16x4*)&embeds_b[(size_t)row * 256 + c4] = o;
    return;
  }
  tid -= 1048576;
  if (tid < 32768) {                         // W1: 512x256
    const f32x4 v = *(const f32x4*)&W1[(size_t)tid * 4];
    bf16x4 o;
    o[0] = (bf16)v[0]; o[1] = (bf16)v[1]; o[2] = (bf16)v[2]; o[3] = (bf16)v[3];
    *(bf16x4*)&W1b[(size_t)tid * 4] = o;
    return;
  }
  tid -= 32768;
  if (tid < 65536) {                         // W2: 512x512
    const f32x4 v = *(const f32x4*)&W2[(size_t)tid * 4];
    bf16x4 o;
    o[0] = (bf16)v[0]; o[1] = (bf16)v[1]; o[2] = (bf16)v[2]; o[3] = (bf16)v[3];
    *(bf16x4*)&W2b[(size_t)tid * 4] = o;
    return;
  }
  tid -= 65536;
  if (tid < 9216)                            // zero 36864 floats
    *(f32x4*)&zeros[(size_t)tid * 4] = (f32x4){0.f, 0.f, 0.f, 0.f};
}

// C[m,n] = epi( sum_k A[m,k]*Bw[n,k] + bias[n] ). 128x128 tile, 8 waves of 32x64,
// K-steps unrolled. SQ: atomically accumulate row sums-of-squares into sq[row].
template <bool RELU, bool SQ, int K>
__global__ __launch_bounds__(512)
void gemm_bt(const bf16* __restrict__ A, const bf16* __restrict__ Bw,
             const float* __restrict__ bias, bf16* __restrict__ C,
             float* __restrict__ sq, int N)
{
  __shared__ __align__(16) bf16 As[128 * 64];
  __shared__ __align__(16) bf16 Bs[128 * 64];
  const int m0 = blockIdx.x * 128;
  const int n0 = blockIdx.y * 128;
  const int t = threadIdx.x;
  const int lane = t & 63;
  const int w = t >> 6;               // 0..7
  const int wm = w >> 1, wn = w & 1;  // wm 0..3 (32-row strip), wn 0..1 (64-col strip)
  const int lr = lane & 15;
  const int lq = lane >> 4;
  const bf16* pA = A + (size_t)m0 * K;
  const bf16* pB = Bw + (size_t)n0 * K;
  const int LDK = K;

  f32x4 acc[2][4];
#pragma unroll
  for (int i = 0; i < 2; ++i)
#pragma unroll
    for (int j = 0; j < 4; ++j)
      acc[i][j] = (f32x4){0.f, 0.f, 0.f, 0.f};

  KSTEP_W8(0) KSTEP_W8(64) KSTEP_W8(128) KSTEP_W8(192)
  if constexpr (K > 256) { KSTEP_W8(256) KSTEP_W8(320) KSTEP_W8(384) KSTEP_W8(448) }

  // C/D layout: col = lane&15, row = (lane>>4)*4 + r
  float bv4[4];
#pragma unroll
  for (int j = 0; j < 4; ++j) {
    const int col = n0 + wn * 64 + j * 16 + lr;
    const float bv = bias[col];
    bv4[j] = bv;
#pragma unroll
    for (int i = 0; i < 2; ++i) {
      const int rbase = m0 + wm * 32 + i * 16 + lq * 4;
#pragma unroll
      for (int r = 0; r < 4; ++r) {
        float v = acc[i][j][r] + bv;
        if (RELU) v = fmaxf(v, 0.0f);
        C[(size_t)(rbase + r) * N + col] = (bf16)v;
      }
    }
  }
  if (SQ) {
#pragma unroll
    for (int i = 0; i < 2; ++i)
#pragma unroll
      for (int r = 0; r < 4; ++r) {
        float s2 = 0.f;
#pragma unroll
        for (int j = 0; j < 4; ++j) {
          const float v = acc[i][j][r] + bv4[j];
          s2 += v * v;
        }
        s2 += __shfl_xor(s2, 1, 64);
        s2 += __shfl_xor(s2, 2, 64);
        s2 += __shfl_xor(s2, 4, 64);
        s2 += __shfl_xor(s2, 8, 64);
        if (lr == 0)
          atomicAdd(&sq[m0 + wm * 32 + i * 16 + lq * 4 + r], s2);
      }
  }
}

// Upper-triangle tile (I,J): T[i,j]=softplus(dot(h_n,h_m)*rsqrt(sq_n)*rsqrt(sq_m)).
// 512 threads / 8 waves, each 32x64 sub-tile. col-sums -> atomic colsum[J]; if I<J
// row-sums -> colsum[I]. grid (8,136): blockIdx.x = batch -> XCD for L2 locality.
__global__ __launch_bounds__(512)
void sim_colsum(const bf16* __restrict__ hidden, const float* __restrict__ sq,
                float* __restrict__ colsum)
{
  __shared__ __align__(16) bf16 As[128 * 64];
  __shared__ __align__(16) bf16 Bs[128 * 64];
  // epilogue arrays alias As (dead after final K-step barrier) -> LDS stays 32768 B
  float* colacc = (float*)As;          // [4][128]
  float* rowacc = (float*)As + 512;    // [2][128]

  const int b = blockIdx.x;
  const int p = blockIdx.y;
  // closed-form triangular decode: p -> (I,J), I<=J, 16 tiles/side
  int I = (int)((33.0f - sqrtf((float)(1089 - 8 * p))) * 0.5f);
  while (p < I * 16 - ((I - 1) * I) / 2) --I;
  while (p >= (I + 1) * 16 - (I * (I + 1)) / 2) ++I;
  const int J = I + p - (I * 16 - ((I - 1) * I) / 2);
  const bool diag = (I == J);
  const bf16* base = hidden + (size_t)b * (2048 * 512);
  const float* sqb = sq + (size_t)b * 2048;
  float* csb = colsum + (size_t)b * 2048;
  const int n0 = I * 128;   // A rows (sim rows)
  const int m0 = J * 128;   // B rows (sim cols)
  const int t = threadIdx.x, lane = t & 63, w = t >> 6;   // w in 0..7
  const int wm = w >> 1, wn = w & 1, lr = lane & 15, lq = lane >> 4;  // wm 0..3
  const bf16* pA = base + (size_t)n0 * 512;
  const bf16* pB = base + (size_t)m0 * 512;
  const int LDK = 512;

  f32x4 acc[2][4];
#pragma unroll
  for (int i = 0; i < 2; ++i)
#pragma unroll
    for (int j = 0; j < 4; ++j)
      acc[i][j] = (f32x4){0.f, 0.f, 0.f, 0.f};

  KSTEP_W8(0) KSTEP_W8(64) KSTEP_W8(128) KSTEP_W8(192)
  KSTEP_W8(256) KSTEP_W8(320) KSTEP_W8(384) KSTEP_W8(448)

  // epilogue: inline inverse norms, softplus(poly), col- and row-sums
  f32x4 rv[2];
#pragma unroll
  for (int i = 0; i < 2; ++i) {
    const f32x4 s4 = *(const f32x4*)&sqb[n0 + wm * 32 + i * 16 + lq * 4];
#pragma unroll
    for (int u = 0; u < 4; ++u) rv[i][u] = rsqrtf(fmaxf(s4[u], 1e-24f));
  }
  float csum[4];
  float rsum[2][4];
#pragma unroll
  for (int j = 0; j < 4; ++j) csum[j] = 0.f;
#pragma unroll
  for (int i = 0; i < 2; ++i)
#pragma unroll
    for (int r = 0; r < 4; ++r) rsum[i][r] = 0.f;

#pragma unroll
  for (int j = 0; j < 4; ++j) {
    const float cv = rsqrtf(fmaxf(sqb[m0 + wn * 64 + j * 16 + lr], 1e-24f));
#pragma unroll
    for (int i = 0; i < 2; ++i)
#pragma unroll
      for (int r = 0; r < 4; ++r) {
        const float x = acc[i][j][r] * rv[i][r] * cv;   // |x| <= ~1
        const float s = softplus_poly(x);
        csum[j] += s;
        rsum[i][r] += s;
      }
  }
  // column sums: reduce over lane-quads (rows): lanes l, l^16, l^32, l^48
#pragma unroll
  for (int j = 0; j < 4; ++j) {
    float s = csum[j];
    s += __shfl_xor(s, 16, 64);
    s += __shfl_xor(s, 32, 64);
    if (lq == 0) colacc[wm * 128 + wn * 64 + j * 16 + lr] = s;
  }
  // row sums: reduce over lr lanes (cols) within quad
  if (!diag) {
#pragma unroll
    for (int i = 0; i < 2; ++i)
#pragma unroll
      for (int r = 0; r < 4; ++r) {
        float s = rsum[i][r];
        s += __shfl_xor(s, 1, 64);
        s += __shfl_xor(s, 2, 64);
        s += __shfl_xor(s, 4, 64);
        s += __shfl_xor(s, 8, 64);
        if (lr == 0) rowacc[wn * 128 + wm * 32 + i * 16 + lq * 4 + r] = s;
      }
  }
  __syncthreads();
  if (t < 128) {
    atomicAdd(&csb[m0 + t], colacc[t] + colacc[128 + t] + colacc[256 + t] + colacc[384 + t]);
  } else if (t < 256 && !diag) {
    const int rr = t - 128;
    atomicAdd(&csb[n0 + rr], rowacc[rr] + rowacc[128 + rr]);
  }
}

// witness[b,d] += sum_{m in 64-chunk} colsum[b,m] * hidden[b,m,d]   (bf16x8 vectorized)
__global__ __launch_bounds__(256)
void witness_partial(const float* __restrict__ colsum, const bf16* __restrict__ hidden,
                     float* __restrict__ witness)
{
  const int mc = blockIdx.x;        // 0..31 (64-m chunks)
  const int b  = blockIdx.y;        // 0..7
  const int t = threadIdx.x;
  const int msub = t >> 6;          // 0..3 (wave-uniform)
  const int dg = t & 63;            // d-group: d = dg*8 .. dg*8+7
  const bf16* hb = hidden + (size_t)b * (2048 * 512);
  const float* cp = colsum + (size_t)b * 2048;
  float acc[8];
#pragma unroll
  for (int u = 0; u < 8; ++u) acc[u] = 0.f;
  const int mbeg = mc * 64 + msub * 16;
#pragma unroll 4
  for (int i = 0; i < 16; ++i) {
    const int m = mbeg + i;
    const float cw = cp[m];
    const bf16x8 v = *(const bf16x8*)&hb[(size_t)m * 512 + dg * 8];
#pragma unroll
    for (int u = 0; u < 8; ++u) acc[u] += cw * (float)v[u];
  }
  __shared__ float red[4][512];
#pragma unroll
  for (int u = 0; u < 8; ++u) red[msub][dg * 8 + u] = acc[u];
  __syncthreads();
  if (msub == 0) {
#pragma unroll
    for (int u = 0; u < 8; ++u) {
      const int d = dg * 8 + u;
      atomicAdd(&witness[(size_t)b * 512 + d],
                red[0][d] + red[1][d] + red[2][d] + red[3][d]);
    }
  }
}

// out[b,g] = bp[g] + (1/2048) * dot(witness[b,:], Wp[g,:])
__global__ __launch_bounds__(64)
void final_proj(const float* __restrict__ witness, const float* __restrict__ Wp,
                const float* __restrict__ bpv, float* __restrict__ out)
{
  const int b = blockIdx.x >> 3;
  const int gc = blockIdx.x & 7;
  const int g = gc * 64 + threadIdx.x;
  __shared__ float wit[512];
#pragma unroll
  for (int u = 0; u < 8; ++u)
    wit[threadIdx.x * 8 + u] = witness[(size_t)b * 512 + threadIdx.x * 8 + u];
  __syncthreads();
  const float* wrow = Wp + (size_t)g * 512;
  float acc = 0.f;
  for (int d0 = 0; d0 < 512; d0 += 4) {
    const f32x4 v = *(const f32x4*)&wrow[d0];
#pragma unroll
    for (int u = 0; u < 4; ++u) acc += v[u] * wit[d0 + u];
  }
  out[(size_t)b * 512 + g] = bpv[g] + acc * (1.0f / 2048.0f);
}

extern "C" void kernel_launch(void* const* d_in, const int* in_sizes, int n_in,
                              void* d_out, int out_size, void* d_ws, size_t ws_size,
                              hipStream_t stream) {
  (void)in_sizes; (void)n_in; (void)out_size; (void)ws_size;
  const int*   tokens = (const int*)d_in[0];
  const float* emb    = (const float*)d_in[1];
  const float* W1     = (const float*)d_in[2];
  const float* b1     = (const float*)d_in[3];
  const float* W2     = (const float*)d_in[4];
  const float* b2     = (const float*)d_in[5];
  const float* Wp     = (const float*)d_in[6];
  const float* bp     = (const float*)d_in[7];
  float* out = (float*)d_out;

  char* w = (char*)d_ws;
  bf16*  embeds_b = (bf16*)(w);                               // 8 MB
  bf16*  W1_b     = (bf16*)(w + (size_t) 8 * 1024 * 1024);    // 256 KB
  bf16*  W2_b     = (bf16*)(w + (size_t) 9 * 1024 * 1024);    // 512 KB
  bf16*  h_buf    = (bf16*)(w + (size_t)10 * 1024 * 1024);    // 16 MB
  bf16*  hidden   = (bf16*)(w + (size_t)26 * 1024 * 1024);    // 16 MB
  char*  zbase    =        (w + (size_t)42 * 1024 * 1024);
  float* sq       = (float*)(zbase);                          // 64 KB  (zeroed in prep)
  float* colsum   = (float*)(zbase + 64 * 1024);              // 64 KB  (zeroed in prep)
  float* witness  = (float*)(zbase + 128 * 1024);             // 16 KB  (zeroed in prep)

  // 1) gather+convert embeds, convert W1/W2, zero accumulators (one kernel)
  fused_prep<<<4516, 256, 0, stream>>>(tokens, emb, W1, W2, embeds_b, W1_b, W2_b, sq);
  // 2) h = relu(embeds @ W1^T + b1)    (8-wave blocks)
  gemm_bt<true,  false, 256><<<dim3(128, 4), 512, 0, stream>>>(embeds_b, W1_b, b1, h_buf, nullptr, 512);
  // 3) hidden = h @ W2^T + b2, fused ||row||^2 partials   (8-wave blocks)
  gemm_bt<false, true,  512><<<dim3(128, 4), 512, 0, stream>>>(h_buf, W2_b, b2, hidden, sq, 512);
  // 4) colsum via symmetric upper-triangle tiles (batch -> XCD), 8-wave blocks
  sim_colsum<<<dim3(8, 136), 512, 0, stream>>>(hidden, sq, colsum);
  // 5) witness partials (vectorized)
  witness_partial<<<dim3(32, 8), 256, 0, stream>>>(colsum, hidden, witness);
  // 6) out = witness/2048 @ Wp^T + bp
  final_proj<<<64, 64, 0, stream>>>(witness, Wp, bp, out);
}